// Round 22
// baseline (140.436 us; speedup 1.0000x reference)
//
#include <hip/hip_runtime.h>

typedef __attribute__((ext_vector_type(8))) short bf16x8;
typedef __attribute__((ext_vector_type(4))) float f32x4;
typedef __attribute__((ext_vector_type(4))) unsigned short u16x4;

// ---------------- helpers ----------------

static __device__ __forceinline__ unsigned short f2bfu(float f) {
  union { float f; unsigned u; } v; v.f = f;
  return (unsigned short)((v.u + 0x7fffu + ((v.u >> 16) & 1u)) >> 16);  // RNE
}

static __device__ __forceinline__ float bfu2f(unsigned short u) {
  union { unsigned u; float f; } v; v.u = ((unsigned)u) << 16; return v.f;
}

static __device__ __forceinline__ void gload_lds16(const void* g, void* l) {
  __builtin_amdgcn_global_load_lds(
      (const __attribute__((address_space(1))) unsigned int*)g,
      (__attribute__((address_space(3))) unsigned int*)l, 16, 0, 0);
}

// 64x64 f32->bf16 transpose tile helper; 16B-wide stores (8 lanes = 128B/row).
// Operates on 256 threads (tid 0..255) with a private 64x65 f32 tile.
static __device__ __forceinline__ void trans_tile(const float* __restrict__ src, int C,
                                                  unsigned short* __restrict__ dst, int ostride,
                                                  int c0, int r0, int tid, float (*tile)[65]) {
  int cc = (tid & 15) * 4, rr = tid >> 4;
#pragma unroll
  for (int i = 0; i < 4; ++i) {
    float4 v = *(const float4*)(src + (size_t)(r0 + rr + i * 16) * C + c0 + cc);
    tile[rr + i * 16][cc + 0] = v.x; tile[rr + i * 16][cc + 1] = v.y;
    tile[rr + i * 16][cc + 2] = v.z; tile[rr + i * 16][cc + 3] = v.w;
  }
  __syncthreads();
  const int seg = tid & 7;                 // 8-elem run along r
  const int ocb = tid >> 3;                // 0..31
#pragma unroll
  for (int i = 0; i < 2; ++i) {
    int oc = ocb + i * 32;
    bf16x8 o;
#pragma unroll
    for (int j = 0; j < 8; ++j) o[j] = (short)f2bfu(tile[seg * 8 + j][oc]);
    *(bf16x8*)(dst + (size_t)(c0 + oc) * ostride + r0 + seg * 8) = o;
  }
}

// ---------------- prep: router only (512 blocks, 4 tokens/block) ----------------
__global__ __launch_bounds__(256) void k_prep(const float* __restrict__ x,
                                              const float* __restrict__ gw,
                                              float* __restrict__ combine,
                                              float* __restrict__ logits,
                                              unsigned short* __restrict__ xb) {
  const int t = blockIdx.x * 4 + (threadIdx.x >> 6);
  const int lane = threadIdx.x & 63;
  const float* xr = x + (size_t)t * 1024;
  unsigned short* xbr = xb + (size_t)t * 1024;
  float acc[16];
#pragma unroll
  for (int e = 0; e < 16; ++e) acc[e] = 0.f;
  for (int h = lane; h < 1024; h += 64) {
    float xv = xr[h];
    xbr[h] = f2bfu(xv);
    const float4* gr = (const float4*)(gw + (size_t)h * 16);
#pragma unroll
    for (int q = 0; q < 4; ++q) {
      float4 g4 = gr[q];
      acc[q * 4 + 0] += xv * g4.x;
      acc[q * 4 + 1] += xv * g4.y;
      acc[q * 4 + 2] += xv * g4.z;
      acc[q * 4 + 3] += xv * g4.w;
    }
  }
#pragma unroll
  for (int e = 0; e < 16; ++e) {
#pragma unroll
    for (int off = 32; off > 0; off >>= 1)
      acc[e] += __shfl_xor(acc[e], off);
  }
  if (lane < 16) logits[(size_t)t * 16 + lane] = acc[lane];

  float m = acc[0];
#pragma unroll
  for (int e = 1; e < 16; ++e) m = fmaxf(m, acc[e]);
  unsigned sel = 0u;
  for (int k = 0; k < 8; ++k) {
    float best = -3.4e38f; int bi = 0;
#pragma unroll
    for (int e = 0; e < 16; ++e)
      if (!((sel >> e) & 1u) && acc[e] > best) { best = acc[e]; bi = e; }
    sel |= 1u << bi;
  }
  float s = 0.f;
#pragma unroll
  for (int e = 0; e < 16; ++e)
    if ((sel >> e) & 1u) s += expf(acc[e] - m);
  float inv = 1.f / s;
  if (lane < 16)
    combine[(size_t)t * 16 + lane] = ((sel >> lane) & 1u) ? expf(acc[lane] - m) * inv : 0.f;
}

// ---------------- scan (16 blocks) + wg/wu transpose tail (4096 blocks) ----------
__global__ __launch_bounds__(256) void k_scan(const float* __restrict__ combine,
                                              unsigned short* __restrict__ idxlist,
                                              int* __restrict__ tokslot,
                                              int* __restrict__ counts,
                                              const float* __restrict__ wga,
                                              const float* __restrict__ wup,
                                              unsigned short* __restrict__ wgt,
                                              unsigned short* __restrict__ wut) {
  __shared__ alignas(16) char smem[16960];         // transpose tile / scan wsum
  const int bid = blockIdx.x;
  const int tid = threadIdx.x;
  if (bid >= 16) {
    const int b2 = bid - 16;                       // 4096 = 32 slabs x 128 tiles
    const int zz = b2 >> 7;
    const int rem = b2 & 127;
    const float* src = (zz < 16 ? wga + (size_t)zz * 524288 : wup + (size_t)(zz - 16) * 524288);
    unsigned short* dst = (zz < 16 ? wgt + (size_t)zz * 524288 : wut + (size_t)(zz - 16) * 524288);
    float (*tile)[65] = (float(*)[65])smem;
    trans_tile(src, 512, dst, 1024, (rem & 7) * 64, (rem >> 3) * 64, tid, tile);
    return;
  }
  int* wsum = (int*)smem;
  const int e = bid;
  const int lane = tid & 63, w = tid >> 6;
  const int t0 = tid * 8;
  int flags = 0, cnt = 0;
#pragma unroll
  for (int j = 0; j < 8; ++j) {
    float c = combine[(size_t)(t0 + j) * 16 + e];
    if (c != 0.f) { flags |= 1 << j; ++cnt; }
  }
  int scan = cnt;
#pragma unroll
  for (int off = 1; off < 64; off <<= 1) {
    int v = __shfl_up(scan, off);
    if (lane >= off) scan += v;
  }
  if (lane == 63) wsum[w] = scan;
  __syncthreads();
  int base = 0;
  for (int i = 0; i < w; ++i) base += wsum[i];
  int pos = base + scan - cnt;
  for (int j = 0; j < 8; ++j) {
    if ((flags >> j) & 1) {
      idxlist[e * 2048 + pos] = (unsigned short)(t0 + j);
      tokslot[(t0 + j) * 16 + e] = pos;
      ++pos;
    } else {
      tokslot[(t0 + j) * 16 + e] = -1;
    }
  }
  if (tid == 255) counts[e] = base + scan;
}

// ---------------- sparse gather gate+up GEMM (BM=256, 8 waves, down-geometry) ----
// Blocks 0..1023: GEMM. BM=256 slots, BN=64 (i), BK=32, 32 k-steps, 8 waves (4m x 2n),
// 3 LDS bufs x 24KB, ONE barrier/step, vmcnt(3) (3 chunks/wave uniform).
// Blocks 1024..2047: wdo->wdt2 transpose, 2 x 64x64 tiles per 512-thr block.
__global__ __launch_bounds__(512) void k_gateup(const unsigned short* __restrict__ xb,
                                                const unsigned short* __restrict__ wgt,
                                                const unsigned short* __restrict__ wut,
                                                const unsigned short* __restrict__ idxlist,
                                                const int* __restrict__ counts,
                                                const float* __restrict__ wdo,
                                                unsigned short* __restrict__ wdt2,
                                                unsigned short* __restrict__ midp) {
  __shared__ alignas(16) char lds[73728];          // 3 x 24K (GEMM) / 2 x 16.6K (transpose)
  const int bid = blockIdx.x;
  const int tid = threadIdx.x;
  if (bid >= 1024) {
    // dual 64x64 transpose tiles: 2048 tiles total = 16 slabs x 128
    const int tiA = (bid - 1024) * 2 + (tid >> 8); // each 256-thr half owns one tile
    const int zz = tiA >> 7;
    const int rem = tiA & 127;
    float (*tile)[65] = (float(*)[65])(lds + (tid >> 8) * 16640);
    trans_tile(wdo + (size_t)zz * 524288, 1024, wdt2 + (size_t)zz * 524288, 512,
               (rem & 15) * 64, (rem >> 4) * 64, tid & 255, tile);
    return;
  }
  const int lb = (bid & 7) * 128 + (bid >> 3);     // XCD-chunked over 1024 GEMM blocks
  const int p = lb & 127, it = lb >> 7;            // p fastest (proven)
  int e = -1, mt = 0, Ne = 0, gb = 0, acc = 0;
#pragma unroll
  for (int i = 0; i < 16; ++i) {
    int c = counts[i];
    int nt = (c + 255) >> 8;
    if (e < 0) {
      if (p < acc + nt) { e = i; mt = p - acc; Ne = c; }
      else gb += c;
    }
    acc += nt;
  }
  if (e < 0) return;
  const int m0 = mt * 256;
  const int i0 = it * 64;

  const int lane = tid & 63;
  const int w = tid >> 6;                          // 0..7
  const int wm = (w >> 1) * 64;                    // 4 m-slices
  const int wn = (w & 1) * 32;                     // 2 n-slices

  const int crow = lane >> 2;                      // row within 16-row chunk
  const int slog = (lane & 3) ^ ((crow >> 1) & 3); // pre-swizzled source 16B slot

  const unsigned short* wge = wgt + (size_t)e * (512 * 1024);
  const unsigned short* wue = wut + (size_t)e * (512 * 1024);

  // 24 chunks of 1KB/buffer: 0-15 A (256 rows), 16-19 Bg, 20-23 Bu. 3 chunks/wave.
  const unsigned short* gsrc[3];
  int loff[3];
#pragma unroll
  for (int q = 0; q < 3; ++q) {
    int c = w * 3 + q;
    loff[q] = c * 1024;
    if (c < 16) {
      int slot = m0 + c * 16 + crow;
      slot = slot < Ne ? slot : Ne - 1;            // clamp: guarded in epilogue
      gsrc[q] = xb + (size_t)idxlist[e * 2048 + slot] * 1024 + slog * 8;
    } else if (c < 20) {
      gsrc[q] = wge + (size_t)(i0 + (c - 16) * 16 + crow) * 1024 + slog * 8;
    } else {
      gsrc[q] = wue + (size_t)(i0 + (c - 20) * 16 + crow) * 1024 + slog * 8;
    }
  }

  auto stage = [&](int buf, int k0) {
    char* base = lds + buf * 24576;
#pragma unroll
    for (int q = 0; q < 3; ++q)
      gload_lds16(gsrc[q] + k0, base + loff[q]);
  };

  const int r0 = lane & 15;
  const int gp16 = ((lane >> 4) ^ ((r0 >> 1) & 3)) << 4;
  const int aoff  = ((wm + r0) << 6) + gp16;
  const int bgoff = 16384 + ((wn + r0) << 6) + gp16;
  const int buoff = 20480 + ((wn + r0) << 6) + gp16;

  f32x4 accg[4][2], accu[4][2];
#pragma unroll
  for (int fm = 0; fm < 4; ++fm)
#pragma unroll
    for (int fn = 0; fn < 2; ++fn) {
      accg[fm][fn] = f32x4{0.f, 0.f, 0.f, 0.f};
      accu[fm][fn] = f32x4{0.f, 0.f, 0.f, 0.f};
    }

  stage(0, 0);
  stage(1, 32);
  int cur = 0;                                     // t % 3
  for (int t = 0; t < 32; ++t) {
    if (t == 31) asm volatile("s_waitcnt vmcnt(0)" ::: "memory");
    else         asm volatile("s_waitcnt vmcnt(3)" ::: "memory");
    __builtin_amdgcn_s_barrier();                  // tile t landed; buf (t+2)%3 free
    const char* base = lds + cur * 24576;
    bf16x8 a[4], bg[2], bu[2];
#pragma unroll
    for (int fm = 0; fm < 4; ++fm) a[fm] = *(const bf16x8*)(base + aoff + fm * 1024);
#pragma unroll
    for (int fn = 0; fn < 2; ++fn) {
      bg[fn] = *(const bf16x8*)(base + bgoff + fn * 1024);
      bu[fn] = *(const bf16x8*)(base + buoff + fn * 1024);
    }
    asm volatile("s_waitcnt lgkmcnt(0)" ::: "memory");
    __builtin_amdgcn_sched_barrier(0);
    if (t + 2 < 32) {
      int nb = cur + 2; if (nb >= 3) nb -= 3;      // (t+2) % 3
      stage(nb, (t + 2) * 32);
    }
    __builtin_amdgcn_s_setprio(1);
#pragma unroll
    for (int fm = 0; fm < 4; ++fm)
#pragma unroll
      for (int fn = 0; fn < 2; ++fn) {
        accg[fm][fn] = __builtin_amdgcn_mfma_f32_16x16x32_bf16(a[fm], bg[fn], accg[fm][fn], 0, 0, 0);
        accu[fm][fn] = __builtin_amdgcn_mfma_f32_16x16x32_bf16(a[fm], bu[fn], accu[fm][fn], 0, 0, 0);
      }
    __builtin_amdgcn_s_setprio(0);
    if (++cur == 3) cur = 0;
  }

  const int gq = lane >> 4;
#pragma unroll
  for (int fm = 0; fm < 4; ++fm) {
#pragma unroll
    for (int jj = 0; jj < 4; ++jj) {
      int slot = m0 + wm + fm * 16 + gq * 4 + jj;
      if (slot >= Ne) continue;
#pragma unroll
      for (int fn = 0; fn < 2; ++fn) {
        float gv = accg[fm][fn][jj];
        float uv = accu[fm][fn][jj];
        float mv = gv / (1.f + __expf(-gv)) * uv;
        midp[(size_t)(gb + slot) * 512 + i0 + wn + fn * 16 + r0] = f2bfu(mv);
      }
    }
  }
}

// ---------------- grouped down GEMM (proven) ----------------
// BM=256 slots, BN=64 (h), BK=32, 16 k-steps, 8 waves, 3 bufs, 1 barrier/step.
__global__ __launch_bounds__(512) void k_down(const unsigned short* __restrict__ midp,
                                              const unsigned short* __restrict__ wdt2,
                                              const int* __restrict__ counts,
                                              unsigned short* __restrict__ dpk) {
  const int lb = (int)(blockIdx.x & 7) * 256 + (int)(blockIdx.x >> 3);  // grid 2048
  const int mt = lb & 7, ht = (lb >> 3) & 15, e = lb >> 7;
  int Ne = counts[e], gb = 0;
#pragma unroll
  for (int i = 0; i < 16; ++i) { int c = counts[i]; if (i < e) gb += c; }
  const int m0 = mt * 256;
  if (m0 >= Ne) return;
  const int h0 = ht * 64;

  __shared__ alignas(16) char lds[61440];   // 3 x (A 16K | B 4K)

  const int tid = threadIdx.x;
  const int lane = tid & 63;
  const int w = tid >> 6;
  const int wm = (w >> 1) * 64;
  const int wn = (w & 1) * 32;

  const int crow = lane >> 2;
  const int slog = (lane & 3) ^ ((crow >> 1) & 3);

  const unsigned short* bsrc = wdt2 + (size_t)e * (512 * 1024);

  const unsigned short* gsrcA[2];
  int loffA[2];
#pragma unroll
  for (int q = 0; q < 2; ++q) {
    int c = q * 8 + w;
    loffA[q] = c * 1024;
    int slot = m0 + c * 16 + crow;
    slot = slot < Ne ? slot : Ne - 1;
    gsrcA[q] = midp + (size_t)(gb + slot) * 512 + slog * 8;
  }
  const unsigned short* gsrcB = nullptr;
  int loffB = 0;
  if (w >= 4) {
    loffB = 16384 + (w - 4) * 1024;
    gsrcB = bsrc + (size_t)(h0 + (w - 4) * 16 + crow) * 512 + slog * 8;
  }

  auto stage = [&](int buf, int k0) {
    char* base = lds + buf * 20480;
#pragma unroll
    for (int q = 0; q < 2; ++q)
      gload_lds16(gsrcA[q] + k0, base + loffA[q]);
    if (gsrcB) gload_lds16(gsrcB + k0, base + loffB);
  };

  const int r0 = lane & 15;
  const int gp16 = ((lane >> 4) ^ ((r0 >> 1) & 3)) << 4;
  const int aoff = ((wm + r0) << 6) + gp16;
  const int boff = 16384 + ((wn + r0) << 6) + gp16;

  f32x4 acc[4][2];
#pragma unroll
  for (int fm = 0; fm < 4; ++fm)
#pragma unroll
    for (int fn = 0; fn < 2; ++fn) acc[fm][fn] = f32x4{0.f, 0.f, 0.f, 0.f};

  stage(0, 0);
  stage(1, 32);
  int cur = 0;
  for (int t = 0; t < 16; ++t) {
    if (t == 15)       asm volatile("s_waitcnt vmcnt(0)" ::: "memory");
    else if (w >= 4)   asm volatile("s_waitcnt vmcnt(3)" ::: "memory");
    else               asm volatile("s_waitcnt vmcnt(2)" ::: "memory");
    __builtin_amdgcn_s_barrier();
    const char* base = lds + cur * 20480;
    bf16x8 a[4], b[2];
#pragma unroll
    for (int fm = 0; fm < 4; ++fm) a[fm] = *(const bf16x8*)(base + aoff + fm * 1024);
#pragma unroll
    for (int fn = 0; fn < 2; ++fn) b[fn] = *(const bf16x8*)(base + boff + fn * 1024);
    asm volatile("s_waitcnt lgkmcnt(0)" ::: "memory");
    __builtin_amdgcn_sched_barrier(0);
    if (t + 2 < 16) {
      int nb = cur + 2; if (nb >= 3) nb -= 3;
      stage(nb, (t + 2) * 32);
    }
    __builtin_amdgcn_s_setprio(1);
#pragma unroll
    for (int fm = 0; fm < 4; ++fm)
#pragma unroll
      for (int fn = 0; fn < 2; ++fn)
        acc[fm][fn] = __builtin_amdgcn_mfma_f32_16x16x32_bf16(a[fm], b[fn], acc[fm][fn], 0, 0, 0);
    __builtin_amdgcn_s_setprio(0);
    if (++cur == 3) cur = 0;
  }

  const int gq = lane >> 4;
#pragma unroll
  for (int fm = 0; fm < 4; ++fm)
#pragma unroll
    for (int jj = 0; jj < 4; ++jj) {
      int slot = m0 + wm + fm * 16 + gq * 4 + jj;
      if (slot >= Ne) continue;
#pragma unroll
      for (int fn = 0; fn < 2; ++fn)
        dpk[(size_t)(gb + slot) * 1024 + h0 + wn + fn * 16 + r0] = f2bfu(acc[fm][fn][jj]);
    }
}

// ---------------- combine ----------------
__global__ __launch_bounds__(128) void k_combine(const unsigned short* __restrict__ dpk,
                                                 const int* __restrict__ tokslot,
                                                 const int* __restrict__ counts,
                                                 const float* __restrict__ combine,
                                                 float* __restrict__ out) {
  __shared__ int gsl[16];
  __shared__ float cws[16];
  const int t = blockIdx.x;
  const int tid = threadIdx.x;
  if (tid < 16) {
    int eb = 0;
    for (int i = 0; i < tid; ++i) eb += counts[i];   // inline ebase
    int sl = tokslot[t * 16 + tid];
    gsl[tid] = (sl >= 0) ? eb + sl : -1;
    cws[tid] = combine[(size_t)t * 16 + tid];
  }
  __syncthreads();
  float av[8];
#pragma unroll
  for (int j = 0; j < 8; ++j) av[j] = 0.f;
#pragma unroll
  for (int e = 0; e < 16; ++e) {
    int g = gsl[e];
    if (g < 0) continue;
    float cw = cws[e];
    bf16x8 v = *(const bf16x8*)(dpk + (size_t)g * 1024 + tid * 8);
#pragma unroll
    for (int j = 0; j < 8; ++j) av[j] += cw * bfu2f((unsigned short)v[j]);
  }
  float4 lo = { av[0], av[1], av[2], av[3] };
  float4 hi = { av[4], av[5], av[6], av[7] };
  float4* op = (float4*)(out + (size_t)t * 1024 + tid * 8);
  op[0] = lo;
  op[1] = hi;
}

// ---------------- launch ----------------
extern "C" void kernel_launch(void* const* d_in, const int* in_sizes, int n_in,
                              void* d_out, int out_size, void* d_ws, size_t ws_size,
                              hipStream_t stream) {
  const float* x   = (const float*)d_in[0];
  const float* gw  = (const float*)d_in[1];
  const float* wga = (const float*)d_in[2];
  const float* wup = (const float*)d_in[3];
  const float* wdo = (const float*)d_in[4];
  float* out = (float*)d_out;
  float* logits = out + (size_t)2048 * 1024;

  char* ws = (char*)d_ws;
  unsigned short* xb   = (unsigned short*)(ws + 0);         //  4 MB
  unsigned short* wgt  = (unsigned short*)(ws + 4194304);   // 16 MB [E][I][H]
  unsigned short* wut  = (unsigned short*)(ws + 20971520);  // 16 MB [E][I][H]
  unsigned short* wdt2 = (unsigned short*)(ws + 37748736);  // 16 MB [E][H][I]
  unsigned short* midp = (unsigned short*)(ws + 54525952);  // 16 MB [16384][512]
  float* combine       = (float*)(ws + 71303168);           // 128 KB
  int* tokslot         = (int*)(ws + 71434240);             // 128 KB
  unsigned short* idxl = (unsigned short*)(ws + 71565312);  // 64 KB
  int* counts          = (int*)(ws + 71630848);             // 64 B
  unsigned short* dpk  = (unsigned short*)(ws + 4194304);   // 32 MB, reuses wgt+wut

  k_prep<<<512, 256, 0, stream>>>(x, gw, combine, logits, xb);
  k_scan<<<4112, 256, 0, stream>>>(combine, idxl, tokslot, counts, wga, wup, wgt, wut);
  k_gateup<<<2048, 512, 0, stream>>>(xb, wgt, wut, idxl, counts, wdo, wdt2, midp);
  k_down<<<2048, 512, 0, stream>>>(midp, wdt2, counts, dpk);
  k_combine<<<2048, 128, 0, stream>>>(dpk, tokslot, counts, combine, out);
}

// Round 23
// 132.894 us; speedup vs baseline: 1.0568x; 1.0568x over previous
//
#include <hip/hip_runtime.h>

typedef __attribute__((ext_vector_type(8))) short bf16x8;
typedef __attribute__((ext_vector_type(4))) float f32x4;
typedef __attribute__((ext_vector_type(4))) unsigned short u16x4;

// ---------------- helpers ----------------

static __device__ __forceinline__ unsigned short f2bfu(float f) {
  union { float f; unsigned u; } v; v.f = f;
  return (unsigned short)((v.u + 0x7fffu + ((v.u >> 16) & 1u)) >> 16);  // RNE
}

static __device__ __forceinline__ float bfu2f(unsigned short u) {
  union { unsigned u; float f; } v; v.u = ((unsigned)u) << 16; return v.f;
}

static __device__ __forceinline__ void gload_lds16(const void* g, void* l) {
  __builtin_amdgcn_global_load_lds(
      (const __attribute__((address_space(1))) unsigned int*)g,
      (__attribute__((address_space(3))) unsigned int*)l, 16, 0, 0);
}

// 64x64 f32->bf16 transpose tile helper; 16B-wide stores (8 lanes = 128B/row)
static __device__ __forceinline__ void trans_tile(const float* __restrict__ src, int C,
                                                  unsigned short* __restrict__ dst, int ostride,
                                                  int c0, int r0, int tid, float (*tile)[65]) {
  int cc = (tid & 15) * 4, rr = tid >> 4;
#pragma unroll
  for (int i = 0; i < 4; ++i) {
    float4 v = *(const float4*)(src + (size_t)(r0 + rr + i * 16) * C + c0 + cc);
    tile[rr + i * 16][cc + 0] = v.x; tile[rr + i * 16][cc + 1] = v.y;
    tile[rr + i * 16][cc + 2] = v.z; tile[rr + i * 16][cc + 3] = v.w;
  }
  __syncthreads();
  const int seg = tid & 7;                 // 8-elem run along r
  const int ocb = tid >> 3;                // 0..31
#pragma unroll
  for (int i = 0; i < 2; ++i) {
    int oc = ocb + i * 32;
    bf16x8 o;
#pragma unroll
    for (int j = 0; j < 8; ++j) o[j] = (short)f2bfu(tile[seg * 8 + j][oc]);
    *(bf16x8*)(dst + (size_t)(c0 + oc) * ostride + r0 + seg * 8) = o;
  }
}

// ---------------- prep: router only (512 blocks, 4 tokens/block) ----------------
__global__ __launch_bounds__(256) void k_prep(const float* __restrict__ x,
                                              const float* __restrict__ gw,
                                              float* __restrict__ combine,
                                              float* __restrict__ logits,
                                              unsigned short* __restrict__ xb) {
  const int t = blockIdx.x * 4 + (threadIdx.x >> 6);
  const int lane = threadIdx.x & 63;
  const float* xr = x + (size_t)t * 1024;
  unsigned short* xbr = xb + (size_t)t * 1024;
  float acc[16];
#pragma unroll
  for (int e = 0; e < 16; ++e) acc[e] = 0.f;
  for (int h = lane; h < 1024; h += 64) {
    float xv = xr[h];
    xbr[h] = f2bfu(xv);
    const float4* gr = (const float4*)(gw + (size_t)h * 16);
#pragma unroll
    for (int q = 0; q < 4; ++q) {
      float4 g4 = gr[q];
      acc[q * 4 + 0] += xv * g4.x;
      acc[q * 4 + 1] += xv * g4.y;
      acc[q * 4 + 2] += xv * g4.z;
      acc[q * 4 + 3] += xv * g4.w;
    }
  }
#pragma unroll
  for (int e = 0; e < 16; ++e) {
#pragma unroll
    for (int off = 32; off > 0; off >>= 1)
      acc[e] += __shfl_xor(acc[e], off);
  }
  if (lane < 16) logits[(size_t)t * 16 + lane] = acc[lane];

  float m = acc[0];
#pragma unroll
  for (int e = 1; e < 16; ++e) m = fmaxf(m, acc[e]);
  unsigned sel = 0u;
  for (int k = 0; k < 8; ++k) {
    float best = -3.4e38f; int bi = 0;
#pragma unroll
    for (int e = 0; e < 16; ++e)
      if (!((sel >> e) & 1u) && acc[e] > best) { best = acc[e]; bi = e; }
    sel |= 1u << bi;
  }
  float s = 0.f;
#pragma unroll
  for (int e = 0; e < 16; ++e)
    if ((sel >> e) & 1u) s += expf(acc[e] - m);
  float inv = 1.f / s;
  if (lane < 16)
    combine[(size_t)t * 16 + lane] = ((sel >> lane) & 1u) ? expf(acc[lane] - m) * inv : 0.f;
}

// ---------------- scan (16 blocks) + wg/wu transpose tail (4096 blocks) ----------
__global__ __launch_bounds__(256) void k_scan(const float* __restrict__ combine,
                                              unsigned short* __restrict__ idxlist,
                                              int* __restrict__ tokslot,
                                              int* __restrict__ counts,
                                              const float* __restrict__ wga,
                                              const float* __restrict__ wup,
                                              unsigned short* __restrict__ wgt,
                                              unsigned short* __restrict__ wut) {
  __shared__ alignas(16) char smem[16960];         // transpose tile / scan wsum
  const int bid = blockIdx.x;
  const int tid = threadIdx.x;
  if (bid >= 16) {
    const int b2 = bid - 16;                       // 4096 = 32 slabs x 128 tiles
    const int zz = b2 >> 7;
    const int rem = b2 & 127;
    const float* src = (zz < 16 ? wga + (size_t)zz * 524288 : wup + (size_t)(zz - 16) * 524288);
    unsigned short* dst = (zz < 16 ? wgt + (size_t)zz * 524288 : wut + (size_t)(zz - 16) * 524288);
    float (*tile)[65] = (float(*)[65])smem;
    trans_tile(src, 512, dst, 1024, (rem & 7) * 64, (rem >> 3) * 64, tid, tile);
    return;
  }
  int* wsum = (int*)smem;
  const int e = bid;
  const int lane = tid & 63, w = tid >> 6;
  const int t0 = tid * 8;
  int flags = 0, cnt = 0;
#pragma unroll
  for (int j = 0; j < 8; ++j) {
    float c = combine[(size_t)(t0 + j) * 16 + e];
    if (c != 0.f) { flags |= 1 << j; ++cnt; }
  }
  int scan = cnt;
#pragma unroll
  for (int off = 1; off < 64; off <<= 1) {
    int v = __shfl_up(scan, off);
    if (lane >= off) scan += v;
  }
  if (lane == 63) wsum[w] = scan;
  __syncthreads();
  int base = 0;
  for (int i = 0; i < w; ++i) base += wsum[i];
  int pos = base + scan - cnt;
  for (int j = 0; j < 8; ++j) {
    if ((flags >> j) & 1) {
      idxlist[e * 2048 + pos] = (unsigned short)(t0 + j);
      tokslot[(t0 + j) * 16 + e] = pos;
      ++pos;
    } else {
      tokslot[(t0 + j) * 16 + e] = -1;
    }
  }
  if (tid == 255) counts[e] = base + scan;
}

// ---------------- sparse gather gate+up GEMM + wd-transpose tail blocks ----------
// Blocks 0..2047: GEMM (BM=128, BN=64, BK=32, 4 waves, 3 bufs, 1 barrier/step).
// Blocks 2048..4095: wdo->wdt2 64x64 transpose tiles (independent; fill idle/tail).
__global__ __launch_bounds__(256) void k_gateup(const unsigned short* __restrict__ xb,
                                                const unsigned short* __restrict__ wgt,
                                                const unsigned short* __restrict__ wut,
                                                const unsigned short* __restrict__ idxlist,
                                                const int* __restrict__ counts,
                                                const float* __restrict__ wdo,
                                                unsigned short* __restrict__ wdt2,
                                                unsigned short* __restrict__ midp) {
  __shared__ alignas(16) char lds[49152];          // 3 x 16K (GEMM) / f32 tile (transpose)
  const int bid = blockIdx.x;
  if (bid >= 2048) {
    const int rem2 = bid - 2048;                   // 2048 = 16 slabs x 128 tiles
    const int zz = rem2 >> 7;
    const int rem = rem2 & 127;
    float (*tile)[65] = (float(*)[65])lds;
    trans_tile(wdo + (size_t)zz * 524288, 1024, wdt2 + (size_t)zz * 524288, 512,
               (rem & 15) * 64, (rem >> 4) * 64, threadIdx.x, tile);
    return;
  }
  const int lb = (bid & 7) * 256 + (bid >> 3);     // XCD-chunked over GEMM blocks
  const int p = lb & 255, it = lb >> 8;            // p fastest (proven)
  int e = -1, mt = 0, Ne = 0, gb = 0, acc = 0;
#pragma unroll
  for (int i = 0; i < 16; ++i) {
    int c = counts[i];
    int nt = (c + 127) >> 7;
    if (e < 0) {
      if (p < acc + nt) { e = i; mt = p - acc; Ne = c; }
      else gb += c;
    }
    acc += nt;
  }
  if (e < 0) return;
  const int m0 = mt * 128;
  const int i0 = it * 64;

  const int tid = threadIdx.x;
  const int lane = tid & 63;
  const int w = tid >> 6;                          // 0..3
  const int wm = (w >> 1) * 64;
  const int wn = (w & 1) * 32;

  const int crow = lane >> 2;                      // row within 16-row chunk
  const int slog = (lane & 3) ^ ((crow >> 1) & 3); // pre-swizzled source 16B slot

  const unsigned short* wge = wgt + (size_t)e * (512 * 1024);
  const unsigned short* wue = wut + (size_t)e * (512 * 1024);

  // 16 chunks of 1KB/buffer: 0-7 A, 8-11 Bg, 12-15 Bu. 4 chunks/wave.
  const unsigned short* gsrc[4];
  int loff[4];
#pragma unroll
  for (int q = 0; q < 4; ++q) {
    int c = w * 4 + q;
    loff[q] = c * 1024;
    if (c < 8) {
      int slot = m0 + c * 16 + crow;
      slot = slot < Ne ? slot : Ne - 1;            // clamp: guarded in epilogue
      gsrc[q] = xb + (size_t)idxlist[e * 2048 + slot] * 1024 + slog * 8;
    } else if (c < 12) {
      gsrc[q] = wge + (size_t)(i0 + (c - 8) * 16 + crow) * 1024 + slog * 8;
    } else {
      gsrc[q] = wue + (size_t)(i0 + (c - 12) * 16 + crow) * 1024 + slog * 8;
    }
  }

  auto stage = [&](int buf, int k0) {
    char* base = lds + buf * 16384;
#pragma unroll
    for (int q = 0; q < 4; ++q)
      gload_lds16(gsrc[q] + k0, base + loff[q]);
  };

  const int r0 = lane & 15;
  const int gp16 = ((lane >> 4) ^ ((r0 >> 1) & 3)) << 4;
  const int aoff  = ((wm + r0) << 6) + gp16;
  const int bgoff = 8192  + ((wn + r0) << 6) + gp16;
  const int buoff = 12288 + ((wn + r0) << 6) + gp16;

  f32x4 accg[4][2], accu[4][2];
#pragma unroll
  for (int fm = 0; fm < 4; ++fm)
#pragma unroll
    for (int fn = 0; fn < 2; ++fn) {
      accg[fm][fn] = f32x4{0.f, 0.f, 0.f, 0.f};
      accu[fm][fn] = f32x4{0.f, 0.f, 0.f, 0.f};
    }

  stage(0, 0);
  stage(1, 32);
  int cur = 0;                                     // t % 3
  for (int t = 0; t < 32; ++t) {
    if (t == 31) asm volatile("s_waitcnt vmcnt(0)" ::: "memory");
    else         asm volatile("s_waitcnt vmcnt(4)" ::: "memory");
    __builtin_amdgcn_s_barrier();                  // tile t landed; buf (t+2)%3 free
    const char* base = lds + cur * 16384;
    bf16x8 a[4], bg[2], bu[2];
#pragma unroll
    for (int fm = 0; fm < 4; ++fm) a[fm] = *(const bf16x8*)(base + aoff + fm * 1024);
#pragma unroll
    for (int fn = 0; fn < 2; ++fn) {
      bg[fn] = *(const bf16x8*)(base + bgoff + fn * 1024);
      bu[fn] = *(const bf16x8*)(base + buoff + fn * 1024);
    }
    asm volatile("s_waitcnt lgkmcnt(0)" ::: "memory");
    __builtin_amdgcn_sched_barrier(0);
    if (t + 2 < 32) {
      int nb = cur + 2; if (nb >= 3) nb -= 3;      // (t+2) % 3
      stage(nb, (t + 2) * 32);
    }
    __builtin_amdgcn_s_setprio(1);
#pragma unroll
    for (int fm = 0; fm < 4; ++fm)
#pragma unroll
      for (int fn = 0; fn < 2; ++fn) {
        accg[fm][fn] = __builtin_amdgcn_mfma_f32_16x16x32_bf16(a[fm], bg[fn], accg[fm][fn], 0, 0, 0);
        accu[fm][fn] = __builtin_amdgcn_mfma_f32_16x16x32_bf16(a[fm], bu[fn], accu[fm][fn], 0, 0, 0);
      }
    __builtin_amdgcn_s_setprio(0);
    if (++cur == 3) cur = 0;
  }

  const int gq = lane >> 4;
#pragma unroll
  for (int fm = 0; fm < 4; ++fm) {
#pragma unroll
    for (int jj = 0; jj < 4; ++jj) {
      int slot = m0 + wm + fm * 16 + gq * 4 + jj;
      if (slot >= Ne) continue;
#pragma unroll
      for (int fn = 0; fn < 2; ++fn) {
        float gv = accg[fm][fn][jj];
        float uv = accu[fm][fn][jj];
        float mv = gv / (1.f + __expf(-gv)) * uv;
        midp[(size_t)(gb + slot) * 512 + i0 + wn + fn * 16 + r0] = f2bfu(mv);
      }
    }
  }
}

// ---------------- grouped down GEMM (proven) ----------------
// BM=256 slots, BN=64 (h), BK=32, 16 k-steps, 8 waves, 3 bufs, 1 barrier/step.
__global__ __launch_bounds__(512) void k_down(const unsigned short* __restrict__ midp,
                                              const unsigned short* __restrict__ wdt2,
                                              const int* __restrict__ counts,
                                              unsigned short* __restrict__ dpk) {
  const int lb = (int)(blockIdx.x & 7) * 256 + (int)(blockIdx.x >> 3);  // grid 2048
  const int mt = lb & 7, ht = (lb >> 3) & 15, e = lb >> 7;
  int Ne = counts[e], gb = 0;
#pragma unroll
  for (int i = 0; i < 16; ++i) { int c = counts[i]; if (i < e) gb += c; }
  const int m0 = mt * 256;
  if (m0 >= Ne) return;
  const int h0 = ht * 64;

  __shared__ alignas(16) char lds[61440];   // 3 x (A 16K | B 4K)

  const int tid = threadIdx.x;
  const int lane = tid & 63;
  const int w = tid >> 6;
  const int wm = (w >> 1) * 64;
  const int wn = (w & 1) * 32;

  const int crow = lane >> 2;
  const int slog = (lane & 3) ^ ((crow >> 1) & 3);

  const unsigned short* bsrc = wdt2 + (size_t)e * (512 * 1024);

  const unsigned short* gsrcA[2];
  int loffA[2];
#pragma unroll
  for (int q = 0; q < 2; ++q) {
    int c = q * 8 + w;
    loffA[q] = c * 1024;
    int slot = m0 + c * 16 + crow;
    slot = slot < Ne ? slot : Ne - 1;
    gsrcA[q] = midp + (size_t)(gb + slot) * 512 + slog * 8;
  }
  const unsigned short* gsrcB = nullptr;
  int loffB = 0;
  if (w >= 4) {
    loffB = 16384 + (w - 4) * 1024;
    gsrcB = bsrc + (size_t)(h0 + (w - 4) * 16 + crow) * 512 + slog * 8;
  }

  auto stage = [&](int buf, int k0) {
    char* base = lds + buf * 20480;
#pragma unroll
    for (int q = 0; q < 2; ++q)
      gload_lds16(gsrcA[q] + k0, base + loffA[q]);
    if (gsrcB) gload_lds16(gsrcB + k0, base + loffB);
  };

  const int r0 = lane & 15;
  const int gp16 = ((lane >> 4) ^ ((r0 >> 1) & 3)) << 4;
  const int aoff = ((wm + r0) << 6) + gp16;
  const int boff = 16384 + ((wn + r0) << 6) + gp16;

  f32x4 acc[4][2];
#pragma unroll
  for (int fm = 0; fm < 4; ++fm)
#pragma unroll
    for (int fn = 0; fn < 2; ++fn) acc[fm][fn] = f32x4{0.f, 0.f, 0.f, 0.f};

  stage(0, 0);
  stage(1, 32);
  int cur = 0;
  for (int t = 0; t < 16; ++t) {
    if (t == 15)       asm volatile("s_waitcnt vmcnt(0)" ::: "memory");
    else if (w >= 4)   asm volatile("s_waitcnt vmcnt(3)" ::: "memory");
    else               asm volatile("s_waitcnt vmcnt(2)" ::: "memory");
    __builtin_amdgcn_s_barrier();
    const char* base = lds + cur * 20480;
    bf16x8 a[4], b[2];
#pragma unroll
    for (int fm = 0; fm < 4; ++fm) a[fm] = *(const bf16x8*)(base + aoff + fm * 1024);
#pragma unroll
    for (int fn = 0; fn < 2; ++fn) b[fn] = *(const bf16x8*)(base + boff + fn * 1024);
    asm volatile("s_waitcnt lgkmcnt(0)" ::: "memory");
    __builtin_amdgcn_sched_barrier(0);
    if (t + 2 < 16) {
      int nb = cur + 2; if (nb >= 3) nb -= 3;
      stage(nb, (t + 2) * 32);
    }
    __builtin_amdgcn_s_setprio(1);
#pragma unroll
    for (int fm = 0; fm < 4; ++fm)
#pragma unroll
      for (int fn = 0; fn < 2; ++fn)
        acc[fm][fn] = __builtin_amdgcn_mfma_f32_16x16x32_bf16(a[fm], b[fn], acc[fm][fn], 0, 0, 0);
    __builtin_amdgcn_s_setprio(0);
    if (++cur == 3) cur = 0;
  }

  const int gq = lane >> 4;
#pragma unroll
  for (int fm = 0; fm < 4; ++fm)
#pragma unroll
    for (int jj = 0; jj < 4; ++jj) {
      int slot = m0 + wm + fm * 16 + gq * 4 + jj;
      if (slot >= Ne) continue;
#pragma unroll
      for (int fn = 0; fn < 2; ++fn)
        dpk[(size_t)(gb + slot) * 1024 + h0 + wn + fn * 16 + r0] = f2bfu(acc[fm][fn][jj]);
    }
}

// ---------------- combine ----------------
__global__ __launch_bounds__(128) void k_combine(const unsigned short* __restrict__ dpk,
                                                 const int* __restrict__ tokslot,
                                                 const int* __restrict__ counts,
                                                 const float* __restrict__ combine,
                                                 float* __restrict__ out) {
  __shared__ int gsl[16];
  __shared__ float cws[16];
  const int t = blockIdx.x;
  const int tid = threadIdx.x;
  if (tid < 16) {
    int eb = 0;
    for (int i = 0; i < tid; ++i) eb += counts[i];   // inline ebase
    int sl = tokslot[t * 16 + tid];
    gsl[tid] = (sl >= 0) ? eb + sl : -1;
    cws[tid] = combine[(size_t)t * 16 + tid];
  }
  __syncthreads();
  float av[8];
#pragma unroll
  for (int j = 0; j < 8; ++j) av[j] = 0.f;
#pragma unroll
  for (int e = 0; e < 16; ++e) {
    int g = gsl[e];
    if (g < 0) continue;
    float cw = cws[e];
    bf16x8 v = *(const bf16x8*)(dpk + (size_t)g * 1024 + tid * 8);
#pragma unroll
    for (int j = 0; j < 8; ++j) av[j] += cw * bfu2f((unsigned short)v[j]);
  }
  float4 lo = { av[0], av[1], av[2], av[3] };
  float4 hi = { av[4], av[5], av[6], av[7] };
  float4* op = (float4*)(out + (size_t)t * 1024 + tid * 8);
  op[0] = lo;
  op[1] = hi;
}

// ---------------- launch ----------------
extern "C" void kernel_launch(void* const* d_in, const int* in_sizes, int n_in,
                              void* d_out, int out_size, void* d_ws, size_t ws_size,
                              hipStream_t stream) {
  const float* x   = (const float*)d_in[0];
  const float* gw  = (const float*)d_in[1];
  const float* wga = (const float*)d_in[2];
  const float* wup = (const float*)d_in[3];
  const float* wdo = (const float*)d_in[4];
  float* out = (float*)d_out;
  float* logits = out + (size_t)2048 * 1024;

  char* ws = (char*)d_ws;
  unsigned short* xb   = (unsigned short*)(ws + 0);         //  4 MB
  unsigned short* wgt  = (unsigned short*)(ws + 4194304);   // 16 MB [E][I][H]
  unsigned short* wut  = (unsigned short*)(ws + 20971520);  // 16 MB [E][I][H]
  unsigned short* wdt2 = (unsigned short*)(ws + 37748736);  // 16 MB [E][H][I]
  unsigned short* midp = (unsigned short*)(ws + 54525952);  // 16 MB [16384][512]
  float* combine       = (float*)(ws + 71303168);           // 128 KB
  int* tokslot         = (int*)(ws + 71434240);             // 128 KB
  unsigned short* idxl = (unsigned short*)(ws + 71565312);  // 64 KB
  int* counts          = (int*)(ws + 71630848);             // 64 B
  unsigned short* dpk  = (unsigned short*)(ws + 4194304);   // 32 MB, reuses wgt+wut

  k_prep<<<512, 256, 0, stream>>>(x, gw, combine, logits, xb);
  k_scan<<<4112, 256, 0, stream>>>(combine, idxl, tokslot, counts, wga, wup, wgt, wut);
  k_gateup<<<4096, 256, 0, stream>>>(xb, wgt, wut, idxl, counts, wdo, wdt2, midp);
  k_down<<<2048, 512, 0, stream>>>(midp, wdt2, counts, dpk);
  k_combine<<<2048, 128, 0, stream>>>(dpk, tokslot, counts, combine, out);
}

// Round 24
// 130.996 us; speedup vs baseline: 1.0721x; 1.0145x over previous
//
#include <hip/hip_runtime.h>

typedef __attribute__((ext_vector_type(8))) short bf16x8;
typedef __attribute__((ext_vector_type(4))) float f32x4;
typedef __attribute__((ext_vector_type(4))) unsigned short u16x4;

// ---------------- helpers ----------------

static __device__ __forceinline__ unsigned short f2bfu(float f) {
  union { float f; unsigned u; } v; v.f = f;
  return (unsigned short)((v.u + 0x7fffu + ((v.u >> 16) & 1u)) >> 16);  // RNE
}

static __device__ __forceinline__ float bfu2f(unsigned short u) {
  union { unsigned u; float f; } v; v.u = ((unsigned)u) << 16; return v.f;
}

static __device__ __forceinline__ void gload_lds16(const void* g, void* l) {
  __builtin_amdgcn_global_load_lds(
      (const __attribute__((address_space(1))) unsigned int*)g,
      (__attribute__((address_space(3))) unsigned int*)l, 16, 0, 0);
}

// 64x64 f32->bf16 transpose tile helper; 16B-wide stores (8 lanes = 128B/row)
static __device__ __forceinline__ void trans_tile(const float* __restrict__ src, int C,
                                                  unsigned short* __restrict__ dst, int ostride,
                                                  int c0, int r0, int tid, float (*tile)[65]) {
  int cc = (tid & 15) * 4, rr = tid >> 4;
#pragma unroll
  for (int i = 0; i < 4; ++i) {
    float4 v = *(const float4*)(src + (size_t)(r0 + rr + i * 16) * C + c0 + cc);
    tile[rr + i * 16][cc + 0] = v.x; tile[rr + i * 16][cc + 1] = v.y;
    tile[rr + i * 16][cc + 2] = v.z; tile[rr + i * 16][cc + 3] = v.w;
  }
  __syncthreads();
  const int seg = tid & 7;                 // 8-elem run along r
  const int ocb = tid >> 3;                // 0..31
#pragma unroll
  for (int i = 0; i < 2; ++i) {
    int oc = ocb + i * 32;
    bf16x8 o;
#pragma unroll
    for (int j = 0; j < 8; ++j) o[j] = (short)f2bfu(tile[seg * 8 + j][oc]);
    *(bf16x8*)(dst + (size_t)(c0 + oc) * ostride + r0 + seg * 8) = o;
  }
}

// ---------------- pre: router (512 blocks) + wg/wu transpose (4096 blocks) --------
// Router and weight transposes are mutually independent; scan (separate launch)
// is the only consumer of router output.
__global__ __launch_bounds__(256) void k_pre(const float* __restrict__ x,
                                             const float* __restrict__ gw,
                                             float* __restrict__ combine,
                                             float* __restrict__ logits,
                                             unsigned short* __restrict__ xb,
                                             const float* __restrict__ wga,
                                             const float* __restrict__ wup,
                                             unsigned short* __restrict__ wgt,
                                             unsigned short* __restrict__ wut) {
  __shared__ alignas(16) char smem[16960];         // transpose tile (router unused)
  const int bid = blockIdx.x;
  const int tid = threadIdx.x;
  if (bid >= 512) {
    const int b2 = bid - 512;                      // 4096 = 32 slabs x 128 tiles
    const int zz = b2 >> 7;
    const int rem = b2 & 127;
    const float* src = (zz < 16 ? wga + (size_t)zz * 524288 : wup + (size_t)(zz - 16) * 524288);
    unsigned short* dst = (zz < 16 ? wgt + (size_t)zz * 524288 : wut + (size_t)(zz - 16) * 524288);
    float (*tile)[65] = (float(*)[65])smem;
    trans_tile(src, 512, dst, 1024, (rem & 7) * 64, (rem >> 3) * 64, tid, tile);
    return;
  }
  // ---- router: 1 token per wave, 4 waves/block ----
  const int t = bid * 4 + (tid >> 6);
  const int lane = tid & 63;
  const float* xr = x + (size_t)t * 1024;
  unsigned short* xbr = xb + (size_t)t * 1024;
  float acc[16];
#pragma unroll
  for (int e = 0; e < 16; ++e) acc[e] = 0.f;
  for (int h = lane; h < 1024; h += 64) {
    float xv = xr[h];
    xbr[h] = f2bfu(xv);
    const float4* gr = (const float4*)(gw + (size_t)h * 16);
#pragma unroll
    for (int q = 0; q < 4; ++q) {
      float4 g4 = gr[q];
      acc[q * 4 + 0] += xv * g4.x;
      acc[q * 4 + 1] += xv * g4.y;
      acc[q * 4 + 2] += xv * g4.z;
      acc[q * 4 + 3] += xv * g4.w;
    }
  }
#pragma unroll
  for (int e = 0; e < 16; ++e) {
#pragma unroll
    for (int off = 32; off > 0; off >>= 1)
      acc[e] += __shfl_xor(acc[e], off);
  }
  if (lane < 16) logits[(size_t)t * 16 + lane] = acc[lane];

  float m = acc[0];
#pragma unroll
  for (int e = 1; e < 16; ++e) m = fmaxf(m, acc[e]);
  unsigned sel = 0u;
  for (int k = 0; k < 8; ++k) {
    float best = -3.4e38f; int bi = 0;
#pragma unroll
    for (int e = 0; e < 16; ++e)
      if (!((sel >> e) & 1u) && acc[e] > best) { best = acc[e]; bi = e; }
    sel |= 1u << bi;
  }
  float s = 0.f;
#pragma unroll
  for (int e = 0; e < 16; ++e)
    if ((sel >> e) & 1u) s += expf(acc[e] - m);
  float inv = 1.f / s;
  if (lane < 16)
    combine[(size_t)t * 16 + lane] = ((sel >> lane) & 1u) ? expf(acc[lane] - m) * inv : 0.f;
}

// ---------------- scan (16 blocks) ----------------
__global__ __launch_bounds__(256) void k_scan(const float* __restrict__ combine,
                                              unsigned short* __restrict__ idxlist,
                                              int* __restrict__ tokslot,
                                              int* __restrict__ counts) {
  __shared__ int wsum[4];
  const int e = blockIdx.x;
  const int tid = threadIdx.x;
  const int lane = tid & 63, w = tid >> 6;
  const int t0 = tid * 8;
  int flags = 0, cnt = 0;
#pragma unroll
  for (int j = 0; j < 8; ++j) {
    float c = combine[(size_t)(t0 + j) * 16 + e];
    if (c != 0.f) { flags |= 1 << j; ++cnt; }
  }
  int scan = cnt;
#pragma unroll
  for (int off = 1; off < 64; off <<= 1) {
    int v = __shfl_up(scan, off);
    if (lane >= off) scan += v;
  }
  if (lane == 63) wsum[w] = scan;
  __syncthreads();
  int base = 0;
  for (int i = 0; i < w; ++i) base += wsum[i];
  int pos = base + scan - cnt;
  for (int j = 0; j < 8; ++j) {
    if ((flags >> j) & 1) {
      idxlist[e * 2048 + pos] = (unsigned short)(t0 + j);
      tokslot[(t0 + j) * 16 + e] = pos;
      ++pos;
    } else {
      tokslot[(t0 + j) * 16 + e] = -1;
    }
  }
  if (tid == 255) counts[e] = base + scan;
}

// ---------------- sparse gather gate+up GEMM + wd-transpose tail blocks ----------
// Blocks 0..2047: GEMM (BM=128, BN=64, BK=32, 4 waves, 3 bufs, 1 barrier/step).
// Blocks 2048..4095: wdo->wdt2 64x64 transpose tiles (independent; fill idle/tail).
__global__ __launch_bounds__(256) void k_gateup(const unsigned short* __restrict__ xb,
                                                const unsigned short* __restrict__ wgt,
                                                const unsigned short* __restrict__ wut,
                                                const unsigned short* __restrict__ idxlist,
                                                const int* __restrict__ counts,
                                                const float* __restrict__ wdo,
                                                unsigned short* __restrict__ wdt2,
                                                unsigned short* __restrict__ midp) {
  __shared__ alignas(16) char lds[49152];          // 3 x 16K (GEMM) / f32 tile (transpose)
  const int bid = blockIdx.x;
  if (bid >= 2048) {
    const int rem2 = bid - 2048;                   // 2048 = 16 slabs x 128 tiles
    const int zz = rem2 >> 7;
    const int rem = rem2 & 127;
    float (*tile)[65] = (float(*)[65])lds;
    trans_tile(wdo + (size_t)zz * 524288, 1024, wdt2 + (size_t)zz * 524288, 512,
               (rem & 15) * 64, (rem >> 4) * 64, threadIdx.x, tile);
    return;
  }
  const int lb = (bid & 7) * 256 + (bid >> 3);     // XCD-chunked over GEMM blocks
  const int p = lb & 255, it = lb >> 8;            // p fastest (proven)
  int e = -1, mt = 0, Ne = 0, gb = 0, acc = 0;
#pragma unroll
  for (int i = 0; i < 16; ++i) {
    int c = counts[i];
    int nt = (c + 127) >> 7;
    if (e < 0) {
      if (p < acc + nt) { e = i; mt = p - acc; Ne = c; }
      else gb += c;
    }
    acc += nt;
  }
  if (e < 0) return;
  const int m0 = mt * 128;
  const int i0 = it * 64;

  const int tid = threadIdx.x;
  const int lane = tid & 63;
  const int w = tid >> 6;                          // 0..3
  const int wm = (w >> 1) * 64;
  const int wn = (w & 1) * 32;

  const int crow = lane >> 2;                      // row within 16-row chunk
  const int slog = (lane & 3) ^ ((crow >> 1) & 3); // pre-swizzled source 16B slot

  const unsigned short* wge = wgt + (size_t)e * (512 * 1024);
  const unsigned short* wue = wut + (size_t)e * (512 * 1024);

  // 16 chunks of 1KB/buffer: 0-7 A, 8-11 Bg, 12-15 Bu. 4 chunks/wave.
  const unsigned short* gsrc[4];
  int loff[4];
#pragma unroll
  for (int q = 0; q < 4; ++q) {
    int c = w * 4 + q;
    loff[q] = c * 1024;
    if (c < 8) {
      int slot = m0 + c * 16 + crow;
      slot = slot < Ne ? slot : Ne - 1;            // clamp: guarded in epilogue
      gsrc[q] = xb + (size_t)idxlist[e * 2048 + slot] * 1024 + slog * 8;
    } else if (c < 12) {
      gsrc[q] = wge + (size_t)(i0 + (c - 8) * 16 + crow) * 1024 + slog * 8;
    } else {
      gsrc[q] = wue + (size_t)(i0 + (c - 12) * 16 + crow) * 1024 + slog * 8;
    }
  }

  auto stage = [&](int buf, int k0) {
    char* base = lds + buf * 16384;
#pragma unroll
    for (int q = 0; q < 4; ++q)
      gload_lds16(gsrc[q] + k0, base + loff[q]);
  };

  const int r0 = lane & 15;
  const int gp16 = ((lane >> 4) ^ ((r0 >> 1) & 3)) << 4;
  const int aoff  = ((wm + r0) << 6) + gp16;
  const int bgoff = 8192  + ((wn + r0) << 6) + gp16;
  const int buoff = 12288 + ((wn + r0) << 6) + gp16;

  f32x4 accg[4][2], accu[4][2];
#pragma unroll
  for (int fm = 0; fm < 4; ++fm)
#pragma unroll
    for (int fn = 0; fn < 2; ++fn) {
      accg[fm][fn] = f32x4{0.f, 0.f, 0.f, 0.f};
      accu[fm][fn] = f32x4{0.f, 0.f, 0.f, 0.f};
    }

  stage(0, 0);
  stage(1, 32);
  int cur = 0;                                     // t % 3
  for (int t = 0; t < 32; ++t) {
    if (t == 31) asm volatile("s_waitcnt vmcnt(0)" ::: "memory");
    else         asm volatile("s_waitcnt vmcnt(4)" ::: "memory");
    __builtin_amdgcn_s_barrier();                  // tile t landed; buf (t+2)%3 free
    const char* base = lds + cur * 16384;
    bf16x8 a[4], bg[2], bu[2];
#pragma unroll
    for (int fm = 0; fm < 4; ++fm) a[fm] = *(const bf16x8*)(base + aoff + fm * 1024);
#pragma unroll
    for (int fn = 0; fn < 2; ++fn) {
      bg[fn] = *(const bf16x8*)(base + bgoff + fn * 1024);
      bu[fn] = *(const bf16x8*)(base + buoff + fn * 1024);
    }
    asm volatile("s_waitcnt lgkmcnt(0)" ::: "memory");
    __builtin_amdgcn_sched_barrier(0);
    if (t + 2 < 32) {
      int nb = cur + 2; if (nb >= 3) nb -= 3;      // (t+2) % 3
      stage(nb, (t + 2) * 32);
    }
    __builtin_amdgcn_s_setprio(1);
#pragma unroll
    for (int fm = 0; fm < 4; ++fm)
#pragma unroll
      for (int fn = 0; fn < 2; ++fn) {
        accg[fm][fn] = __builtin_amdgcn_mfma_f32_16x16x32_bf16(a[fm], bg[fn], accg[fm][fn], 0, 0, 0);
        accu[fm][fn] = __builtin_amdgcn_mfma_f32_16x16x32_bf16(a[fm], bu[fn], accu[fm][fn], 0, 0, 0);
      }
    __builtin_amdgcn_s_setprio(0);
    if (++cur == 3) cur = 0;
  }

  const int gq = lane >> 4;
#pragma unroll
  for (int fm = 0; fm < 4; ++fm) {
#pragma unroll
    for (int jj = 0; jj < 4; ++jj) {
      int slot = m0 + wm + fm * 16 + gq * 4 + jj;
      if (slot >= Ne) continue;
#pragma unroll
      for (int fn = 0; fn < 2; ++fn) {
        float gv = accg[fm][fn][jj];
        float uv = accu[fm][fn][jj];
        float mv = gv / (1.f + __expf(-gv)) * uv;
        midp[(size_t)(gb + slot) * 512 + i0 + wn + fn * 16 + r0] = f2bfu(mv);
      }
    }
  }
}

// ---------------- grouped down GEMM (proven) ----------------
// BM=256 slots, BN=64 (h), BK=32, 16 k-steps, 8 waves, 3 bufs, 1 barrier/step.
__global__ __launch_bounds__(512) void k_down(const unsigned short* __restrict__ midp,
                                              const unsigned short* __restrict__ wdt2,
                                              const int* __restrict__ counts,
                                              unsigned short* __restrict__ dpk) {
  const int lb = (int)(blockIdx.x & 7) * 256 + (int)(blockIdx.x >> 3);  // grid 2048
  const int mt = lb & 7, ht = (lb >> 3) & 15, e = lb >> 7;
  int Ne = counts[e], gb = 0;
#pragma unroll
  for (int i = 0; i < 16; ++i) { int c = counts[i]; if (i < e) gb += c; }
  const int m0 = mt * 256;
  if (m0 >= Ne) return;
  const int h0 = ht * 64;

  __shared__ alignas(16) char lds[61440];   // 3 x (A 16K | B 4K)

  const int tid = threadIdx.x;
  const int lane = tid & 63;
  const int w = tid >> 6;
  const int wm = (w >> 1) * 64;
  const int wn = (w & 1) * 32;

  const int crow = lane >> 2;
  const int slog = (lane & 3) ^ ((crow >> 1) & 3);

  const unsigned short* bsrc = wdt2 + (size_t)e * (512 * 1024);

  const unsigned short* gsrcA[2];
  int loffA[2];
#pragma unroll
  for (int q = 0; q < 2; ++q) {
    int c = q * 8 + w;
    loffA[q] = c * 1024;
    int slot = m0 + c * 16 + crow;
    slot = slot < Ne ? slot : Ne - 1;
    gsrcA[q] = midp + (size_t)(gb + slot) * 512 + slog * 8;
  }
  const unsigned short* gsrcB = nullptr;
  int loffB = 0;
  if (w >= 4) {
    loffB = 16384 + (w - 4) * 1024;
    gsrcB = bsrc + (size_t)(h0 + (w - 4) * 16 + crow) * 512 + slog * 8;
  }

  auto stage = [&](int buf, int k0) {
    char* base = lds + buf * 20480;
#pragma unroll
    for (int q = 0; q < 2; ++q)
      gload_lds16(gsrcA[q] + k0, base + loffA[q]);
    if (gsrcB) gload_lds16(gsrcB + k0, base + loffB);
  };

  const int r0 = lane & 15;
  const int gp16 = ((lane >> 4) ^ ((r0 >> 1) & 3)) << 4;
  const int aoff = ((wm + r0) << 6) + gp16;
  const int boff = 16384 + ((wn + r0) << 6) + gp16;

  f32x4 acc[4][2];
#pragma unroll
  for (int fm = 0; fm < 4; ++fm)
#pragma unroll
    for (int fn = 0; fn < 2; ++fn) acc[fm][fn] = f32x4{0.f, 0.f, 0.f, 0.f};

  stage(0, 0);
  stage(1, 32);
  int cur = 0;
  for (int t = 0; t < 16; ++t) {
    if (t == 15)       asm volatile("s_waitcnt vmcnt(0)" ::: "memory");
    else if (w >= 4)   asm volatile("s_waitcnt vmcnt(3)" ::: "memory");
    else               asm volatile("s_waitcnt vmcnt(2)" ::: "memory");
    __builtin_amdgcn_s_barrier();
    const char* base = lds + cur * 20480;
    bf16x8 a[4], b[2];
#pragma unroll
    for (int fm = 0; fm < 4; ++fm) a[fm] = *(const bf16x8*)(base + aoff + fm * 1024);
#pragma unroll
    for (int fn = 0; fn < 2; ++fn) b[fn] = *(const bf16x8*)(base + boff + fn * 1024);
    asm volatile("s_waitcnt lgkmcnt(0)" ::: "memory");
    __builtin_amdgcn_sched_barrier(0);
    if (t + 2 < 16) {
      int nb = cur + 2; if (nb >= 3) nb -= 3;
      stage(nb, (t + 2) * 32);
    }
    __builtin_amdgcn_s_setprio(1);
#pragma unroll
    for (int fm = 0; fm < 4; ++fm)
#pragma unroll
      for (int fn = 0; fn < 2; ++fn)
        acc[fm][fn] = __builtin_amdgcn_mfma_f32_16x16x32_bf16(a[fm], b[fn], acc[fm][fn], 0, 0, 0);
    __builtin_amdgcn_s_setprio(0);
    if (++cur == 3) cur = 0;
  }

  const int gq = lane >> 4;
#pragma unroll
  for (int fm = 0; fm < 4; ++fm)
#pragma unroll
    for (int jj = 0; jj < 4; ++jj) {
      int slot = m0 + wm + fm * 16 + gq * 4 + jj;
      if (slot >= Ne) continue;
#pragma unroll
      for (int fn = 0; fn < 2; ++fn)
        dpk[(size_t)(gb + slot) * 1024 + h0 + wn + fn * 16 + r0] = f2bfu(acc[fm][fn][jj]);
    }
}

// ---------------- combine ----------------
__global__ __launch_bounds__(128) void k_combine(const unsigned short* __restrict__ dpk,
                                                 const int* __restrict__ tokslot,
                                                 const int* __restrict__ counts,
                                                 const float* __restrict__ combine,
                                                 float* __restrict__ out) {
  __shared__ int gsl[16];
  __shared__ float cws[16];
  const int t = blockIdx.x;
  const int tid = threadIdx.x;
  if (tid < 16) {
    int eb = 0;
    for (int i = 0; i < tid; ++i) eb += counts[i];   // inline ebase
    int sl = tokslot[t * 16 + tid];
    gsl[tid] = (sl >= 0) ? eb + sl : -1;
    cws[tid] = combine[(size_t)t * 16 + tid];
  }
  __syncthreads();
  float av[8];
#pragma unroll
  for (int j = 0; j < 8; ++j) av[j] = 0.f;
#pragma unroll
  for (int e = 0; e < 16; ++e) {
    int g = gsl[e];
    if (g < 0) continue;
    float cw = cws[e];
    bf16x8 v = *(const bf16x8*)(dpk + (size_t)g * 1024 + tid * 8);
#pragma unroll
    for (int j = 0; j < 8; ++j) av[j] += cw * bfu2f((unsigned short)v[j]);
  }
  float4 lo = { av[0], av[1], av[2], av[3] };
  float4 hi = { av[4], av[5], av[6], av[7] };
  float4* op = (float4*)(out + (size_t)t * 1024 + tid * 8);
  op[0] = lo;
  op[1] = hi;
}

// ---------------- launch ----------------
extern "C" void kernel_launch(void* const* d_in, const int* in_sizes, int n_in,
                              void* d_out, int out_size, void* d_ws, size_t ws_size,
                              hipStream_t stream) {
  const float* x   = (const float*)d_in[0];
  const float* gw  = (const float*)d_in[1];
  const float* wga = (const float*)d_in[2];
  const float* wup = (const float*)d_in[3];
  const float* wdo = (const float*)d_in[4];
  float* out = (float*)d_out;
  float* logits = out + (size_t)2048 * 1024;

  char* ws = (char*)d_ws;
  unsigned short* xb   = (unsigned short*)(ws + 0);         //  4 MB
  unsigned short* wgt  = (unsigned short*)(ws + 4194304);   // 16 MB [E][I][H]
  unsigned short* wut  = (unsigned short*)(ws + 20971520);  // 16 MB [E][I][H]
  unsigned short* wdt2 = (unsigned short*)(ws + 37748736);  // 16 MB [E][H][I]
  unsigned short* midp = (unsigned short*)(ws + 54525952);  // 16 MB [16384][512]
  float* combine       = (float*)(ws + 71303168);           // 128 KB
  int* tokslot         = (int*)(ws + 71434240);             // 128 KB
  unsigned short* idxl = (unsigned short*)(ws + 71565312);  // 64 KB
  int* counts          = (int*)(ws + 71630848);             // 64 B
  unsigned short* dpk  = (unsigned short*)(ws + 4194304);   // 32 MB, reuses wgt+wut

  k_pre<<<4608, 256, 0, stream>>>(x, gw, combine, logits, xb, wga, wup, wgt, wut);
  k_scan<<<16, 256, 0, stream>>>(combine, idxl, tokslot, counts);
  k_gateup<<<4096, 256, 0, stream>>>(xb, wgt, wut, idxl, counts, wdo, wdt2, midp);
  k_down<<<2048, 512, 0, stream>>>(midp, wdt2, counts, dpk);
  k_combine<<<2048, 128, 0, stream>>>(dpk, tokslot, counts, combine, out);
}

// Round 25
// 130.984 us; speedup vs baseline: 1.0722x; 1.0001x over previous
//
#include <hip/hip_runtime.h>

typedef __attribute__((ext_vector_type(8))) short bf16x8;
typedef __attribute__((ext_vector_type(4))) float f32x4;
typedef __attribute__((ext_vector_type(4))) unsigned short u16x4;

// ---------------- helpers ----------------

static __device__ __forceinline__ unsigned short f2bfu(float f) {
  union { float f; unsigned u; } v; v.f = f;
  return (unsigned short)((v.u + 0x7fffu + ((v.u >> 16) & 1u)) >> 16);  // RNE
}

static __device__ __forceinline__ float bfu2f(unsigned short u) {
  union { unsigned u; float f; } v; v.u = ((unsigned)u) << 16; return v.f;
}

static __device__ __forceinline__ void gload_lds16(const void* g, void* l) {
  __builtin_amdgcn_global_load_lds(
      (const __attribute__((address_space(1))) unsigned int*)g,
      (__attribute__((address_space(3))) unsigned int*)l, 16, 0, 0);
}

// 64x64 f32->bf16 transpose tile helper; 16B-wide stores (8 lanes = 128B/row)
static __device__ __forceinline__ void trans_tile(const float* __restrict__ src, int C,
                                                  unsigned short* __restrict__ dst, int ostride,
                                                  int c0, int r0, int tid, float (*tile)[65]) {
  int cc = (tid & 15) * 4, rr = tid >> 4;
#pragma unroll
  for (int i = 0; i < 4; ++i) {
    float4 v = *(const float4*)(src + (size_t)(r0 + rr + i * 16) * C + c0 + cc);
    tile[rr + i * 16][cc + 0] = v.x; tile[rr + i * 16][cc + 1] = v.y;
    tile[rr + i * 16][cc + 2] = v.z; tile[rr + i * 16][cc + 3] = v.w;
  }
  __syncthreads();
  const int seg = tid & 7;                 // 8-elem run along r
  const int ocb = tid >> 3;                // 0..31
#pragma unroll
  for (int i = 0; i < 2; ++i) {
    int oc = ocb + i * 32;
    bf16x8 o;
#pragma unroll
    for (int j = 0; j < 8; ++j) o[j] = (short)f2bfu(tile[seg * 8 + j][oc]);
    *(bf16x8*)(dst + (size_t)(c0 + oc) * ostride + r0 + seg * 8) = o;
  }
}

// ---------------- pre: router (512 blocks) + wg/wu transpose (4096 blocks) --------
// Router and weight transposes are mutually independent; scan (separate launch)
// is the only consumer of router output.
__global__ __launch_bounds__(256) void k_pre(const float* __restrict__ x,
                                             const float* __restrict__ gw,
                                             float* __restrict__ combine,
                                             float* __restrict__ logits,
                                             unsigned short* __restrict__ xb,
                                             const float* __restrict__ wga,
                                             const float* __restrict__ wup,
                                             unsigned short* __restrict__ wgt,
                                             unsigned short* __restrict__ wut) {
  __shared__ alignas(16) char smem[16960];         // transpose tile (router unused)
  const int bid = blockIdx.x;
  const int tid = threadIdx.x;
  if (bid >= 512) {
    const int b2 = bid - 512;                      // 4096 = 32 slabs x 128 tiles
    const int zz = b2 >> 7;
    const int rem = b2 & 127;
    const float* src = (zz < 16 ? wga + (size_t)zz * 524288 : wup + (size_t)(zz - 16) * 524288);
    unsigned short* dst = (zz < 16 ? wgt + (size_t)zz * 524288 : wut + (size_t)(zz - 16) * 524288);
    float (*tile)[65] = (float(*)[65])smem;
    trans_tile(src, 512, dst, 1024, (rem & 7) * 64, (rem >> 3) * 64, tid, tile);
    return;
  }
  // ---- router: 1 token per wave, 4 waves/block ----
  const int t = bid * 4 + (tid >> 6);
  const int lane = tid & 63;
  const float* xr = x + (size_t)t * 1024;
  unsigned short* xbr = xb + (size_t)t * 1024;
  float acc[16];
#pragma unroll
  for (int e = 0; e < 16; ++e) acc[e] = 0.f;
  for (int h = lane; h < 1024; h += 64) {
    float xv = xr[h];
    xbr[h] = f2bfu(xv);
    const float4* gr = (const float4*)(gw + (size_t)h * 16);
#pragma unroll
    for (int q = 0; q < 4; ++q) {
      float4 g4 = gr[q];
      acc[q * 4 + 0] += xv * g4.x;
      acc[q * 4 + 1] += xv * g4.y;
      acc[q * 4 + 2] += xv * g4.z;
      acc[q * 4 + 3] += xv * g4.w;
    }
  }
#pragma unroll
  for (int e = 0; e < 16; ++e) {
#pragma unroll
    for (int off = 32; off > 0; off >>= 1)
      acc[e] += __shfl_xor(acc[e], off);
  }
  if (lane < 16) logits[(size_t)t * 16 + lane] = acc[lane];

  float m = acc[0];
#pragma unroll
  for (int e = 1; e < 16; ++e) m = fmaxf(m, acc[e]);
  unsigned sel = 0u;
  for (int k = 0; k < 8; ++k) {
    float best = -3.4e38f; int bi = 0;
#pragma unroll
    for (int e = 0; e < 16; ++e)
      if (!((sel >> e) & 1u) && acc[e] > best) { best = acc[e]; bi = e; }
    sel |= 1u << bi;
  }
  float s = 0.f;
#pragma unroll
  for (int e = 0; e < 16; ++e)
    if ((sel >> e) & 1u) s += expf(acc[e] - m);
  float inv = 1.f / s;
  if (lane < 16)
    combine[(size_t)t * 16 + lane] = ((sel >> lane) & 1u) ? expf(acc[lane] - m) * inv : 0.f;
}

// ---------------- scan (16 blocks) ----------------
__global__ __launch_bounds__(256) void k_scan(const float* __restrict__ combine,
                                              unsigned short* __restrict__ idxlist,
                                              int* __restrict__ tokslot,
                                              int* __restrict__ counts) {
  __shared__ int wsum[4];
  const int e = blockIdx.x;
  const int tid = threadIdx.x;
  const int lane = tid & 63, w = tid >> 6;
  const int t0 = tid * 8;
  int flags = 0, cnt = 0;
#pragma unroll
  for (int j = 0; j < 8; ++j) {
    float c = combine[(size_t)(t0 + j) * 16 + e];
    if (c != 0.f) { flags |= 1 << j; ++cnt; }
  }
  int scan = cnt;
#pragma unroll
  for (int off = 1; off < 64; off <<= 1) {
    int v = __shfl_up(scan, off);
    if (lane >= off) scan += v;
  }
  if (lane == 63) wsum[w] = scan;
  __syncthreads();
  int base = 0;
  for (int i = 0; i < w; ++i) base += wsum[i];
  int pos = base + scan - cnt;
  for (int j = 0; j < 8; ++j) {
    if ((flags >> j) & 1) {
      idxlist[e * 2048 + pos] = (unsigned short)(t0 + j);
      tokslot[(t0 + j) * 16 + e] = pos;
      ++pos;
    } else {
      tokslot[(t0 + j) * 16 + e] = -1;
    }
  }
  if (tid == 255) counts[e] = base + scan;
}

// ---------------- sparse gather gate+up GEMM + wd-transpose tail blocks ----------
// Blocks 0..2047: GEMM (BM=128, BN=64, BK=32, 4 waves, 3 bufs, 1 barrier/step).
// Blocks 2048..4095: wdo->wdt2 64x64 transpose tiles (independent; fill idle/tail).
__global__ __launch_bounds__(256) void k_gateup(const unsigned short* __restrict__ xb,
                                                const unsigned short* __restrict__ wgt,
                                                const unsigned short* __restrict__ wut,
                                                const unsigned short* __restrict__ idxlist,
                                                const int* __restrict__ counts,
                                                const float* __restrict__ wdo,
                                                unsigned short* __restrict__ wdt2,
                                                unsigned short* __restrict__ midp) {
  __shared__ alignas(16) char lds[49152];          // 3 x 16K (GEMM) / f32 tile (transpose)
  const int bid = blockIdx.x;
  if (bid >= 2048) {
    const int rem2 = bid - 2048;                   // 2048 = 16 slabs x 128 tiles
    const int zz = rem2 >> 7;
    const int rem = rem2 & 127;
    float (*tile)[65] = (float(*)[65])lds;
    trans_tile(wdo + (size_t)zz * 524288, 1024, wdt2 + (size_t)zz * 524288, 512,
               (rem & 15) * 64, (rem >> 4) * 64, threadIdx.x, tile);
    return;
  }
  const int lb = (bid & 7) * 256 + (bid >> 3);     // XCD-chunked over GEMM blocks
  const int p = lb & 255, it = lb >> 8;            // p fastest (proven)
  int e = -1, mt = 0, Ne = 0, gb = 0, acc = 0;
#pragma unroll
  for (int i = 0; i < 16; ++i) {
    int c = counts[i];
    int nt = (c + 127) >> 7;
    if (e < 0) {
      if (p < acc + nt) { e = i; mt = p - acc; Ne = c; }
      else gb += c;
    }
    acc += nt;
  }
  if (e < 0) return;
  const int m0 = mt * 128;
  const int i0 = it * 64;

  const int tid = threadIdx.x;
  const int lane = tid & 63;
  const int w = tid >> 6;                          // 0..3
  const int wm = (w >> 1) * 64;
  const int wn = (w & 1) * 32;

  const int crow = lane >> 2;                      // row within 16-row chunk
  const int slog = (lane & 3) ^ ((crow >> 1) & 3); // pre-swizzled source 16B slot

  const unsigned short* wge = wgt + (size_t)e * (512 * 1024);
  const unsigned short* wue = wut + (size_t)e * (512 * 1024);

  // 16 chunks of 1KB/buffer: 0-7 A, 8-11 Bg, 12-15 Bu. 4 chunks/wave.
  const unsigned short* gsrc[4];
  int loff[4];
#pragma unroll
  for (int q = 0; q < 4; ++q) {
    int c = w * 4 + q;
    loff[q] = c * 1024;
    if (c < 8) {
      int slot = m0 + c * 16 + crow;
      slot = slot < Ne ? slot : Ne - 1;            // clamp: guarded in epilogue
      gsrc[q] = xb + (size_t)idxlist[e * 2048 + slot] * 1024 + slog * 8;
    } else if (c < 12) {
      gsrc[q] = wge + (size_t)(i0 + (c - 8) * 16 + crow) * 1024 + slog * 8;
    } else {
      gsrc[q] = wue + (size_t)(i0 + (c - 12) * 16 + crow) * 1024 + slog * 8;
    }
  }

  auto stage = [&](int buf, int k0) {
    char* base = lds + buf * 16384;
#pragma unroll
    for (int q = 0; q < 4; ++q)
      gload_lds16(gsrc[q] + k0, base + loff[q]);
  };

  const int r0 = lane & 15;
  const int gp16 = ((lane >> 4) ^ ((r0 >> 1) & 3)) << 4;
  const int aoff  = ((wm + r0) << 6) + gp16;
  const int bgoff = 8192  + ((wn + r0) << 6) + gp16;
  const int buoff = 12288 + ((wn + r0) << 6) + gp16;

  f32x4 accg[4][2], accu[4][2];
#pragma unroll
  for (int fm = 0; fm < 4; ++fm)
#pragma unroll
    for (int fn = 0; fn < 2; ++fn) {
      accg[fm][fn] = f32x4{0.f, 0.f, 0.f, 0.f};
      accu[fm][fn] = f32x4{0.f, 0.f, 0.f, 0.f};
    }

  stage(0, 0);
  stage(1, 32);
  int cur = 0;                                     // t % 3
  for (int t = 0; t < 32; ++t) {
    if (t == 31) asm volatile("s_waitcnt vmcnt(0)" ::: "memory");
    else         asm volatile("s_waitcnt vmcnt(4)" ::: "memory");
    __builtin_amdgcn_s_barrier();                  // tile t landed; buf (t+2)%3 free
    const char* base = lds + cur * 16384;
    bf16x8 a[4], bg[2], bu[2];
#pragma unroll
    for (int fm = 0; fm < 4; ++fm) a[fm] = *(const bf16x8*)(base + aoff + fm * 1024);
#pragma unroll
    for (int fn = 0; fn < 2; ++fn) {
      bg[fn] = *(const bf16x8*)(base + bgoff + fn * 1024);
      bu[fn] = *(const bf16x8*)(base + buoff + fn * 1024);
    }
    asm volatile("s_waitcnt lgkmcnt(0)" ::: "memory");
    __builtin_amdgcn_sched_barrier(0);
    if (t + 2 < 32) {
      int nb = cur + 2; if (nb >= 3) nb -= 3;      // (t+2) % 3
      stage(nb, (t + 2) * 32);
    }
    __builtin_amdgcn_s_setprio(1);
#pragma unroll
    for (int fm = 0; fm < 4; ++fm)
#pragma unroll
      for (int fn = 0; fn < 2; ++fn) {
        accg[fm][fn] = __builtin_amdgcn_mfma_f32_16x16x32_bf16(a[fm], bg[fn], accg[fm][fn], 0, 0, 0);
        accu[fm][fn] = __builtin_amdgcn_mfma_f32_16x16x32_bf16(a[fm], bu[fn], accu[fm][fn], 0, 0, 0);
      }
    __builtin_amdgcn_s_setprio(0);
    if (++cur == 3) cur = 0;
  }

  const int gq = lane >> 4;
#pragma unroll
  for (int fm = 0; fm < 4; ++fm) {
#pragma unroll
    for (int jj = 0; jj < 4; ++jj) {
      int slot = m0 + wm + fm * 16 + gq * 4 + jj;
      if (slot >= Ne) continue;
#pragma unroll
      for (int fn = 0; fn < 2; ++fn) {
        float gv = accg[fm][fn][jj];
        float uv = accu[fm][fn][jj];
        float mv = gv / (1.f + __expf(-gv)) * uv;
        midp[(size_t)(gb + slot) * 512 + i0 + wn + fn * 16 + r0] = f2bfu(mv);
      }
    }
  }
}

// ---------------- grouped down GEMM (proven) ----------------
// BM=256 slots, BN=64 (h), BK=32, 16 k-steps, 8 waves, 3 bufs, 1 barrier/step.
__global__ __launch_bounds__(512) void k_down(const unsigned short* __restrict__ midp,
                                              const unsigned short* __restrict__ wdt2,
                                              const int* __restrict__ counts,
                                              unsigned short* __restrict__ dpk) {
  const int lb = (int)(blockIdx.x & 7) * 256 + (int)(blockIdx.x >> 3);  // grid 2048
  const int mt = lb & 7, ht = (lb >> 3) & 15, e = lb >> 7;
  int Ne = counts[e], gb = 0;
#pragma unroll
  for (int i = 0; i < 16; ++i) { int c = counts[i]; if (i < e) gb += c; }
  const int m0 = mt * 256;
  if (m0 >= Ne) return;
  const int h0 = ht * 64;

  __shared__ alignas(16) char lds[61440];   // 3 x (A 16K | B 4K)

  const int tid = threadIdx.x;
  const int lane = tid & 63;
  const int w = tid >> 6;
  const int wm = (w >> 1) * 64;
  const int wn = (w & 1) * 32;

  const int crow = lane >> 2;
  const int slog = (lane & 3) ^ ((crow >> 1) & 3);

  const unsigned short* bsrc = wdt2 + (size_t)e * (512 * 1024);

  const unsigned short* gsrcA[2];
  int loffA[2];
#pragma unroll
  for (int q = 0; q < 2; ++q) {
    int c = q * 8 + w;
    loffA[q] = c * 1024;
    int slot = m0 + c * 16 + crow;
    slot = slot < Ne ? slot : Ne - 1;
    gsrcA[q] = midp + (size_t)(gb + slot) * 512 + slog * 8;
  }
  const unsigned short* gsrcB = nullptr;
  int loffB = 0;
  if (w >= 4) {
    loffB = 16384 + (w - 4) * 1024;
    gsrcB = bsrc + (size_t)(h0 + (w - 4) * 16 + crow) * 512 + slog * 8;
  }

  auto stage = [&](int buf, int k0) {
    char* base = lds + buf * 20480;
#pragma unroll
    for (int q = 0; q < 2; ++q)
      gload_lds16(gsrcA[q] + k0, base + loffA[q]);
    if (gsrcB) gload_lds16(gsrcB + k0, base + loffB);
  };

  const int r0 = lane & 15;
  const int gp16 = ((lane >> 4) ^ ((r0 >> 1) & 3)) << 4;
  const int aoff = ((wm + r0) << 6) + gp16;
  const int boff = 16384 + ((wn + r0) << 6) + gp16;

  f32x4 acc[4][2];
#pragma unroll
  for (int fm = 0; fm < 4; ++fm)
#pragma unroll
    for (int fn = 0; fn < 2; ++fn) acc[fm][fn] = f32x4{0.f, 0.f, 0.f, 0.f};

  stage(0, 0);
  stage(1, 32);
  int cur = 0;
  for (int t = 0; t < 16; ++t) {
    if (t == 15)       asm volatile("s_waitcnt vmcnt(0)" ::: "memory");
    else if (w >= 4)   asm volatile("s_waitcnt vmcnt(3)" ::: "memory");
    else               asm volatile("s_waitcnt vmcnt(2)" ::: "memory");
    __builtin_amdgcn_s_barrier();
    const char* base = lds + cur * 20480;
    bf16x8 a[4], b[2];
#pragma unroll
    for (int fm = 0; fm < 4; ++fm) a[fm] = *(const bf16x8*)(base + aoff + fm * 1024);
#pragma unroll
    for (int fn = 0; fn < 2; ++fn) b[fn] = *(const bf16x8*)(base + boff + fn * 1024);
    asm volatile("s_waitcnt lgkmcnt(0)" ::: "memory");
    __builtin_amdgcn_sched_barrier(0);
    if (t + 2 < 16) {
      int nb = cur + 2; if (nb >= 3) nb -= 3;
      stage(nb, (t + 2) * 32);
    }
    __builtin_amdgcn_s_setprio(1);
#pragma unroll
    for (int fm = 0; fm < 4; ++fm)
#pragma unroll
      for (int fn = 0; fn < 2; ++fn)
        acc[fm][fn] = __builtin_amdgcn_mfma_f32_16x16x32_bf16(a[fm], b[fn], acc[fm][fn], 0, 0, 0);
    __builtin_amdgcn_s_setprio(0);
    if (++cur == 3) cur = 0;
  }

  const int gq = lane >> 4;
#pragma unroll
  for (int fm = 0; fm < 4; ++fm)
#pragma unroll
    for (int jj = 0; jj < 4; ++jj) {
      int slot = m0 + wm + fm * 16 + gq * 4 + jj;
      if (slot >= Ne) continue;
#pragma unroll
      for (int fn = 0; fn < 2; ++fn)
        dpk[(size_t)(gb + slot) * 1024 + h0 + wn + fn * 16 + r0] = f2bfu(acc[fm][fn][jj]);
    }
}

// ---------------- combine ----------------
__global__ __launch_bounds__(128) void k_combine(const unsigned short* __restrict__ dpk,
                                                 const int* __restrict__ tokslot,
                                                 const int* __restrict__ counts,
                                                 const float* __restrict__ combine,
                                                 float* __restrict__ out) {
  __shared__ int gsl[16];
  __shared__ float cws[16];
  const int t = blockIdx.x;
  const int tid = threadIdx.x;
  if (tid < 16) {
    int eb = 0;
    for (int i = 0; i < tid; ++i) eb += counts[i];   // inline ebase
    int sl = tokslot[t * 16 + tid];
    gsl[tid] = (sl >= 0) ? eb + sl : -1;
    cws[tid] = combine[(size_t)t * 16 + tid];
  }
  __syncthreads();
  float av[8];
#pragma unroll
  for (int j = 0; j < 8; ++j) av[j] = 0.f;
#pragma unroll
  for (int e = 0; e < 16; ++e) {
    int g = gsl[e];
    if (g < 0) continue;
    float cw = cws[e];
    bf16x8 v = *(const bf16x8*)(dpk + (size_t)g * 1024 + tid * 8);
#pragma unroll
    for (int j = 0; j < 8; ++j) av[j] += cw * bfu2f((unsigned short)v[j]);
  }
  float4 lo = { av[0], av[1], av[2], av[3] };
  float4 hi = { av[4], av[5], av[6], av[7] };
  float4* op = (float4*)(out + (size_t)t * 1024 + tid * 8);
  op[0] = lo;
  op[1] = hi;
}

// ---------------- launch ----------------
extern "C" void kernel_launch(void* const* d_in, const int* in_sizes, int n_in,
                              void* d_out, int out_size, void* d_ws, size_t ws_size,
                              hipStream_t stream) {
  const float* x   = (const float*)d_in[0];
  const float* gw  = (const float*)d_in[1];
  const float* wga = (const float*)d_in[2];
  const float* wup = (const float*)d_in[3];
  const float* wdo = (const float*)d_in[4];
  float* out = (float*)d_out;
  float* logits = out + (size_t)2048 * 1024;

  char* ws = (char*)d_ws;
  unsigned short* xb   = (unsigned short*)(ws + 0);         //  4 MB
  unsigned short* wgt  = (unsigned short*)(ws + 4194304);   // 16 MB [E][I][H]
  unsigned short* wut  = (unsigned short*)(ws + 20971520);  // 16 MB [E][I][H]
  unsigned short* wdt2 = (unsigned short*)(ws + 37748736);  // 16 MB [E][H][I]
  unsigned short* midp = (unsigned short*)(ws + 54525952);  // 16 MB [16384][512]
  float* combine       = (float*)(ws + 71303168);           // 128 KB
  int* tokslot         = (int*)(ws + 71434240);             // 128 KB
  unsigned short* idxl = (unsigned short*)(ws + 71565312);  // 64 KB
  int* counts          = (int*)(ws + 71630848);             // 64 B
  unsigned short* dpk  = (unsigned short*)(ws + 4194304);   // 32 MB, reuses wgt+wut

  k_pre<<<4608, 256, 0, stream>>>(x, gw, combine, logits, xb, wga, wup, wgt, wut);
  k_scan<<<16, 256, 0, stream>>>(combine, idxl, tokslot, counts);
  k_gateup<<<4096, 256, 0, stream>>>(xb, wgt, wut, idxl, counts, wdo, wdt2, midp);
  k_down<<<2048, 512, 0, stream>>>(midp, wdt2, counts, dpk);
  k_combine<<<2048, 128, 0, stream>>>(dpk, tokslot, counts, combine, out);
}